// Round 7
// baseline (69.624 us; speedup 1.0000x reference)
//
#include <hip/hip_runtime.h>

// Grouped conv: x (1,48,56,56) f32, w (24,96,7) f32, groups=2.
// y[o,h,wo] = sum_{i<24,k<7} x[24g+i, h, wo+k-3] * w[i, o%96, k]   (pad 3 on W)
// out[o,h,:] = y[o, (h - shift) mod 56, :]   (jnp.roll along H)
//
// R7: R6 (scalar weights, no LDS, no barrier — 65.9 us) + DPP synthesis of
// the L/R window float4s from the neighbor lane's M (row_shr:1 / row_shl:1,
// 16-lane rows == our row groups). Global loads per wave: 72 -> 24. This is
// R5's idea re-run WITHOUT R5's confound (its prefetch was serialized behind
// an LDS-staging __syncthreads vmcnt(0) drain; R6 removed barrier entirely).
// bound_ctrl zeroes the left edge for free; rz cndmask kept for the right.
// xv values and FMA order bitwise-identical to R6.

#define Hh 56
#define Wd 56
#define HWsz (Hh * Wd)
#define CI 24
#define KW 7
#define OCB 4   // output channels per block (2 per wave)
#define PF 12   // prefetch depth in input channels (M-only)

__device__ __forceinline__ float dpp_shr1(float v) {   // lane n <- lane n-1 within 16-lane row; lane 0 -> 0
    return __int_as_float(__builtin_amdgcn_update_dpp(
        0, __float_as_int(v), 0x111, 0xF, 0xF, true));
}
__device__ __forceinline__ float dpp_shl1(float v) {   // lane n <- lane n+1 within 16-lane row; lane 15 -> 0
    return __int_as_float(__builtin_amdgcn_update_dpp(
        0, __float_as_int(v), 0x101, 0xF, 0xF, true));
}

__global__ __launch_bounds__(128) void conv7_roll_kernel(
    const float* __restrict__ x,
    const float* __restrict__ w,
    const int* __restrict__ shift_p,
    float* __restrict__ out)
{
    const int tid  = threadIdx.x;
    const int wid  = __builtin_amdgcn_readfirstlane(tid >> 6); // wave-uniform
    const int lane = tid & 63;
    const int rl   = lane >> 4;         // 0..3  row within 4-row group
    const int c4r  = lane & 15;         // 0..15 (14,15 inactive)
    const int c4   = c4r < 13 ? c4r : 13;

    const int shift = shift_p[0];

    const int obase = blockIdx.x * OCB; // 0,4,...,188 (never straddles group)
    const int g     = obase / 96;
    const int ocb96 = obase - g * 96;

    const int h_out = blockIdx.y * 4 + rl;
    int hi = (h_out - shift) % Hh;
    if (hi < 0) hi += Hh;

    // M loads stay inside row hi (cols 4c4..4c4+3, c4 <= 13).
    const float* xg = x + g * (CI * HWsz) + hi * Wd + c4 * 4;
    const bool rz = (c4 >= 13);

    // Uniform weight base pointers for this wave's two output channels.
    const float* w0p = w + (ocb96 + wid * 2    ) * KW;
    const float* w1p = w + (ocb96 + wid * 2 + 1) * KW;

    float a0[4] = {0.f, 0.f, 0.f, 0.f};
    float a1[4] = {0.f, 0.f, 0.f, 0.f};

    // Prologue: issue M loads for ci = 0..PF-1 (12 float4 in flight).
    float4 Mb[PF];
    #pragma unroll
    for (int p = 0; p < PF; ++p)
        Mb[p] = *(const float4*)(xg + p * HWsz);

    #pragma unroll
    for (int ci = 0; ci < CI; ++ci) {
        const int s = ci % PF;          // compile-time after full unroll
        float4 M = Mb[s];
        if (ci + PF < CI)               // re-issue this slot for ci+PF
            Mb[s] = *(const float4*)(xg + (ci + PF) * HWsz);

        // L = M of lane c4-1 (left edge auto-zeroed by bound_ctrl).
        float4 L, R;
        L.x = dpp_shr1(M.x); L.y = dpp_shr1(M.y);
        L.z = dpp_shr1(M.z); L.w = dpp_shr1(M.w);
        // R = M of lane c4+1; lane 13 must see zero (lane 14 holds clamped data).
        R.x = dpp_shl1(M.x); R.y = dpp_shl1(M.y);
        R.z = dpp_shl1(M.z); R.w = dpp_shl1(M.w);
        if (rz) { R.x = 0.f; R.y = 0.f; R.z = 0.f; R.w = 0.f; }

        // Window cols 4c4-4 .. 4c4+7; output col 4c4+j uses xv[1+j+k].
        float xv[12] = {L.x, L.y, L.z, L.w, M.x, M.y, M.z, M.w, R.x, R.y, R.z, R.w};

        // Wave-uniform weight reads -> s_load, broadcast via SGPR operands.
        float w0[KW], w1[KW];
        #pragma unroll
        for (int k = 0; k < KW; ++k) {
            w0[k] = w0p[ci * (96 * KW) + k];
            w1[k] = w1p[ci * (96 * KW) + k];
        }

        #pragma unroll
        for (int k = 0; k < KW; ++k) {
            #pragma unroll
            for (int j = 0; j < 4; ++j) {
                a0[j] += xv[1 + j + k] * w0[k];
                a1[j] += xv[1 + j + k] * w1[k];
            }
        }
    }

    if (c4r < 14) {
        const int o0 = obase + wid * 2;
        float* op0 = out + o0 * HWsz + h_out * Wd + c4 * 4;
        float* op1 = op0 + HWsz;
        *(float4*)op0 = make_float4(a0[0], a0[1], a0[2], a0[3]);
        *(float4*)op1 = make_float4(a1[0], a1[1], a1[2], a1[3]);
    }
}

extern "C" void kernel_launch(void* const* d_in, const int* in_sizes, int n_in,
                              void* d_out, int out_size, void* d_ws, size_t ws_size,
                              hipStream_t stream)
{
    const float* x     = (const float*)d_in[0];
    const float* w     = (const float*)d_in[1];
    const int*   shift = (const int*)d_in[2];
    float*       out   = (float*)d_out;

    dim3 grid(48, 14);   // 192/4 oc-groups x 56/4 row-groups
    conv7_roll_kernel<<<grid, 128, 0, stream>>>(x, w, shift, out);
}

// Round 8
// 66.666 us; speedup vs baseline: 1.0444x; 1.0444x over previous
//
#include <hip/hip_runtime.h>

// Grouped conv: x (1,48,56,56) f32, w (24,96,7) f32, groups=2.
// y[o,h,wo] = sum_{i<24,k<7} x[24g+i, h, wo+k-3] * w[i, o%96, k]   (pad 3 on W)
// out[o,h,:] = y[o, (h - shift) mod 56, :]   (jnp.roll along H)
//
// R8 = R6 verbatim (best measured: 65.9 us). R7's DPP experiment regressed
// (+3.7 us): synthesizing L/R from M serializes M-load -> DPP -> FMA and
// defeats the independent-stream prefetch; reverted. Structure:
//  - grid 48x14, 128 thr (2 waves), 2 oc/wave, lane = 4 rows x 14 float4-strips
//  - x: L/M/R independent float4 streams, depth-8 channel prefetch
//  - weights: wave-uniform -> scalar s_load path, SGPR operands in v_fmac
//  - no LDS, no barrier (vmcnt(0) drain was R5's hidden cost)

#define Hh 56
#define Wd 56
#define HWsz (Hh * Wd)
#define CI 24
#define KW 7
#define OCB 4   // output channels per block (2 per wave)
#define PF 8    // prefetch depth in input channels

__global__ __launch_bounds__(128) void conv7_roll_kernel(
    const float* __restrict__ x,
    const float* __restrict__ w,
    const int* __restrict__ shift_p,
    float* __restrict__ out)
{
    const int tid  = threadIdx.x;
    const int wid  = __builtin_amdgcn_readfirstlane(tid >> 6); // wave-uniform in SGPR
    const int lane = tid & 63;
    const int rl   = lane >> 4;         // 0..3  row within 4-row group
    const int c4r  = lane & 15;         // 0..15 (14,15 inactive)
    const int c4   = c4r < 13 ? c4r : 13;

    const int shift = shift_p[0];

    const int obase = blockIdx.x * OCB; // 0,4,...,188 (never straddles group)
    const int g     = obase / 96;
    const int ocb96 = obase - g * 96;

    const int h_out = blockIdx.y * 4 + rl;
    int hi = (h_out - shift) % Hh;
    if (hi < 0) hi += Hh;

    // All loads stay inside row hi after clamping.
    const float* xg = x + g * (CI * HWsz) + hi * Wd + c4 * 4;
    const int dl = (c4 > 0  ? -4 : 0);
    const int dr = (c4 < 13 ?  4 : 0);
    const bool lz = (c4 == 0);
    const bool rz = (c4 >= 13);

    // Uniform weight base pointers for this wave's two output channels.
    const float* w0p = w + (ocb96 + wid * 2    ) * KW;
    const float* w1p = w + (ocb96 + wid * 2 + 1) * KW;

    float a0[4] = {0.f, 0.f, 0.f, 0.f};
    float a1[4] = {0.f, 0.f, 0.f, 0.f};

    // Prologue: issue loads for ci = 0..PF-1 (24 float4 in flight).
    float4 Mb[PF], Lb[PF], Rb[PF];
    #pragma unroll
    for (int p = 0; p < PF; ++p) {
        const float* b = xg + p * HWsz;
        Mb[p] = *(const float4*)b;
        Lb[p] = *(const float4*)(b + dl);
        Rb[p] = *(const float4*)(b + dr);
    }

    #pragma unroll
    for (int ci = 0; ci < CI; ++ci) {
        const int s = ci % PF;          // compile-time after full unroll
        float4 M = Mb[s];
        float4 L = Lb[s];
        float4 R = Rb[s];
        if (ci + PF < CI) {             // re-issue this slot for ci+PF
            const float* b = xg + (ci + PF) * HWsz;
            Mb[s] = *(const float4*)b;
            Lb[s] = *(const float4*)(b + dl);
            Rb[s] = *(const float4*)(b + dr);
        }
        if (lz) { L.x = 0.f; L.y = 0.f; L.z = 0.f; L.w = 0.f; }
        if (rz) { R.x = 0.f; R.y = 0.f; R.z = 0.f; R.w = 0.f; }
        // Window cols 4c4-4 .. 4c4+7; output col 4c4+j uses xv[1+j+k].
        float xv[12] = {L.x, L.y, L.z, L.w, M.x, M.y, M.z, M.w, R.x, R.y, R.z, R.w};

        // Wave-uniform weight reads -> s_load, broadcast via SGPR operands.
        float w0[KW], w1[KW];
        #pragma unroll
        for (int k = 0; k < KW; ++k) {
            w0[k] = w0p[ci * (96 * KW) + k];
            w1[k] = w1p[ci * (96 * KW) + k];
        }

        #pragma unroll
        for (int k = 0; k < KW; ++k) {
            #pragma unroll
            for (int j = 0; j < 4; ++j) {
                a0[j] += xv[1 + j + k] * w0[k];
                a1[j] += xv[1 + j + k] * w1[k];
            }
        }
    }

    if (c4r < 14) {
        const int o0 = obase + wid * 2;
        float* op0 = out + o0 * HWsz + h_out * Wd + c4 * 4;
        float* op1 = op0 + HWsz;
        *(float4*)op0 = make_float4(a0[0], a0[1], a0[2], a0[3]);
        *(float4*)op1 = make_float4(a1[0], a1[1], a1[2], a1[3]);
    }
}

extern "C" void kernel_launch(void* const* d_in, const int* in_sizes, int n_in,
                              void* d_out, int out_size, void* d_ws, size_t ws_size,
                              hipStream_t stream)
{
    const float* x     = (const float*)d_in[0];
    const float* w     = (const float*)d_in[1];
    const int*   shift = (const int*)d_in[2];
    float*       out   = (float*)d_out;

    dim3 grid(48, 14);   // 192/4 oc-groups x 56/4 row-groups
    conv7_roll_kernel<<<grid, 128, 0, stream>>>(x, w, shift, out);
}